// Round 1
// baseline (174.845 us; speedup 1.0000x reference)
//
#include <hip/hip_runtime.h>
#include <hip/hip_bf16.h>

// out[M=131072, N=512] = x[M, K=512] @ W^T[N=512, K=512] + bias[N]
// fp32 in/out; bf16 MFMA compute (fp32 accum).
//
// BM=128, BN=512 (full N -> x read exactly once from HBM), BK=32, 16 K-steps.
// 512 threads = 8 waves (2 x 4), each wave computes 64x128 via 16x16x32 MFMA
// with 4x8 fragment repeats. Double-buffered LDS, reg-staged with inline
// fp32->bf16 conversion, XOR swizzle ((row>>1)&3) on 16B chunks for
// conflict-free ds_read_b128.

#define M_TOTAL 131072
#define KDIM 512
#define NDIM 512
#define BM 128
#define BK 32
#define NKSTEP 16

typedef __attribute__((ext_vector_type(8))) short bf16x8;
typedef __attribute__((ext_vector_type(4))) float f32x4;
typedef __attribute__((ext_vector_type(4))) float fv4;
typedef __attribute__((ext_vector_type(4))) int iv4;

__device__ __forceinline__ unsigned short f2bf(float f) {
    union { float f; unsigned u; } c; c.f = f;
    unsigned r = c.u + 0x7fffu + ((c.u >> 16) & 1u);  // round-to-nearest-even
    return (unsigned short)(r >> 16);
}

__device__ __forceinline__ iv4 pack8(fv4 lo, fv4 hi) {
    union { unsigned short us[8]; iv4 v; } p;
#pragma unroll
    for (int i = 0; i < 4; ++i) {
        p.us[i]     = f2bf(lo[i]);
        p.us[4 + i] = f2bf(hi[i]);
    }
    return p.v;
}

__global__ __launch_bounds__(512, 2) void linear_bf16_kernel(
    const float* __restrict__ x, const float* __restrict__ w,
    const float* __restrict__ bias, float* __restrict__ out) {
    __shared__ __attribute__((aligned(16))) unsigned short lds_a[2][BM * BK];   // 2 x 8 KB
    __shared__ __attribute__((aligned(16))) unsigned short lds_b[2][NDIM * BK]; // 2 x 32 KB

    const int tid  = threadIdx.x;
    const int lane = tid & 63;
    const int wid  = tid >> 6;
    const int wrow = wid >> 2;   // 0..1 -> 64-row block
    const int wcol = wid & 3;    // 0..3 -> 128-col block
    const int fr   = lane & 15;
    const int fc   = lane >> 4;  // 0..3, 8-elem k-chunk

    const int rowbase = blockIdx.x * BM;

    // ---- staging coords: thread t handles tile row t>>2, 8-elem chunk t&3 ----
    const int srow  = tid >> 2;   // 0..127
    const int sslot = tid & 3;    // 0..3
    const int swz   = sslot ^ ((srow >> 1) & 3);
    const int st_a  = srow * BK + swz * 8;   // short index into a 128x32 tile

    const float* xrow  = x + (rowbase + srow) * KDIM + sslot * 8;
    const float* wrow0 = w + srow * KDIM + sslot * 8;  // pass p adds p*128 rows

    f32x4 acc[4][8];
#pragma unroll
    for (int m = 0; m < 4; ++m)
#pragma unroll
        for (int n = 0; n < 8; ++n)
            acc[m][n] = (f32x4){0.f, 0.f, 0.f, 0.f};

    fv4 ra0, ra1, rb0[4], rb1[4];

    auto LOADS = [&](int kb) {
        const fv4* xs = reinterpret_cast<const fv4*>(xrow + kb * BK);
        ra0 = xs[0];
        ra1 = xs[1];
#pragma unroll
        for (int p = 0; p < 4; ++p) {
            const fv4* ws = reinterpret_cast<const fv4*>(wrow0 + p * 128 * KDIM + kb * BK);
            rb0[p] = ws[0];
            rb1[p] = ws[1];
        }
    };
    auto WRITES = [&](int buf) {
        *reinterpret_cast<iv4*>(&lds_a[buf][st_a]) = pack8(ra0, ra1);
#pragma unroll
        for (int p = 0; p < 4; ++p)
            *reinterpret_cast<iv4*>(&lds_b[buf][p * 128 * BK + st_a]) = pack8(rb0[p], rb1[p]);
    };

    LOADS(0);
    WRITES(0);
    __syncthreads();

    // frag read offsets (swizzle depends only on fr since block row bases are x16)
    const int fswz = (fc ^ ((fr >> 1) & 3)) * 8;
    const int aoff = (wrow * 64 + fr) * BK + fswz;
    const int boff = (wcol * 128 + fr) * BK + fswz;

    for (int kb = 0; kb < NKSTEP; ++kb) {
        const int cur = kb & 1;
        if (kb + 1 < NKSTEP) LOADS(kb + 1);  // issue next-tile global loads early

        const unsigned short* pa = &lds_a[cur][aoff];
        const unsigned short* pb = &lds_b[cur][boff];
        bf16x8 af[4], bfv[8];
#pragma unroll
        for (int m = 0; m < 4; ++m)
            af[m] = *reinterpret_cast<const bf16x8*>(pa + m * 16 * BK);
#pragma unroll
        for (int n = 0; n < 8; ++n)
            bfv[n] = *reinterpret_cast<const bf16x8*>(pb + n * 16 * BK);
#pragma unroll
        for (int m = 0; m < 4; ++m)
#pragma unroll
            for (int n = 0; n < 8; ++n)
                acc[m][n] = __builtin_amdgcn_mfma_f32_16x16x32_bf16(af[m], bfv[n], acc[m][n], 0, 0, 0);

        if (kb + 1 < NKSTEP) WRITES(cur ^ 1);  // convert + ds_write after MFMA (loads hidden)
        __syncthreads();
    }

    // ---- epilogue: bias + store ----
    float bv[8];
#pragma unroll
    for (int n = 0; n < 8; ++n)
        bv[n] = bias[wcol * 128 + n * 16 + fr];

    float* obase = out + (rowbase + wrow * 64 + fc * 4) * NDIM + wcol * 128 + fr;
#pragma unroll
    for (int m = 0; m < 4; ++m)
#pragma unroll
        for (int j = 0; j < 4; ++j) {
            float* orow = obase + (m * 16 + j) * NDIM;
#pragma unroll
            for (int n = 0; n < 8; ++n)
                orow[n * 16] = acc[m][n][j] + bv[n];
        }
}

extern "C" void kernel_launch(void* const* d_in, const int* in_sizes, int n_in,
                              void* d_out, int out_size, void* d_ws, size_t ws_size,
                              hipStream_t stream) {
    const float* x    = (const float*)d_in[0];
    const float* w    = (const float*)d_in[1];
    const float* bias = (const float*)d_in[2];
    float* out        = (float*)d_out;

    dim3 grid(M_TOTAL / BM);  // 1024
    dim3 block(512);
    hipLaunchKernelGGL(linear_bf16_kernel, grid, block, 0, stream, x, w, bias, out);
}

// Round 2
// 139.858 us; speedup vs baseline: 1.2502x; 1.2502x over previous
//
#include <hip/hip_runtime.h>
#include <hip/hip_bf16.h>

// out[M=131072, N=512] = x[M, K=512] @ W^T[N=512, K=512] + bias[N]
// fp32 in/out; bf16 MFMA (fp32 accum).
//
// Kernel 1: repack W fp32 -> bf16 MFMA-fragment layout in d_ws (512 KB).
// Kernel 2: GEMM. BM=128 x BN=512 (x read once), BK=32, 16 K-steps.
//   1024 threads = 16 waves (2 wrow x 8 wcol), wave tile 64x64 (acc = 64 regs,
//   target <=128 regs/wave -> 4 waves/SIMD). A double-buffered in LDS (2x8 KB,
//   XOR-swizzled, measured conflict-free), B-fragments loaded straight from
//   the repacked global buffer (L2-resident, 1 KB coalesced per wave-instr).
//   x prefetch is 2 steps deep (ping-pong regs ra0/ra1).

#define M_TOTAL 131072
#define KDIM 512
#define NDIM 512
#define BM 128
#define BK 32
#define NKSTEP 16

typedef __attribute__((ext_vector_type(8))) short bf16x8;
typedef __attribute__((ext_vector_type(4))) float f32x4;
typedef __attribute__((ext_vector_type(4))) float fv4;
typedef __attribute__((ext_vector_type(4))) int iv4;
typedef __attribute__((ext_vector_type(2))) int iv2;

__device__ __forceinline__ unsigned short f2bf(float f) {
    union { float f; unsigned u; } c; c.f = f;
    unsigned r = c.u + 0x7fffu + ((c.u >> 16) & 1u);  // RNE
    return (unsigned short)(r >> 16);
}

// wf[((t*16+kb)*64 + l)*8 + j] = bf16( W[t*16 + (l&15)][kb*32 + (l>>4)*8 + j] )
// t = n-tile (0..31), kb = k-step (0..15), l = lane.
__global__ void repack_w_kernel(const float* __restrict__ w,
                                unsigned short* __restrict__ wf) {
    const int gtid = blockIdx.x * 256 + threadIdx.x;  // 0..32767
    const int tk = gtid >> 6;   // t*16 + kb
    const int l  = gtid & 63;
    const int n  = (tk >> 4) * 16 + (l & 15);
    const int k0 = (tk & 15) * 32 + (l >> 4) * 8;
    const fv4* src = reinterpret_cast<const fv4*>(w + n * KDIM + k0);
    fv4 lo = src[0], hi = src[1];
    union { unsigned short us[8]; iv4 v; } p;
#pragma unroll
    for (int i = 0; i < 4; ++i) { p.us[i] = f2bf(lo[i]); p.us[4 + i] = f2bf(hi[i]); }
    *reinterpret_cast<iv4*>(wf + tk * 512 + l * 8) = p.v;
}

__global__ __launch_bounds__(1024) void linear_bf16_kernel(
    const float* __restrict__ x, const unsigned short* __restrict__ wf,
    const float* __restrict__ bias, float* __restrict__ out) {
    __shared__ __attribute__((aligned(16))) unsigned short lds_a[2][BM * BK];  // 2 x 8 KB

    const int tid  = threadIdx.x;
    const int lane = tid & 63;
    const int wid  = tid >> 6;   // 0..15
    const int wrow = wid >> 3;   // 0..1  -> 64-row block
    const int wcol = wid & 7;    // 0..7  -> 64-col block
    const int fr   = lane & 15;
    const int fc   = lane >> 4;  // k-chunk 0..3

    const int rowbase = blockIdx.x * BM;

    // ---- A staging: thread t -> row t>>3, 4-float quarter t&7 ----
    const int srow = tid >> 3;   // 0..127
    const int sq   = tid & 7;    // 0..7
    const float* xptr = x + (rowbase + srow) * KDIM + sq * 4;
    // physical chunk swizzle (16B granule): c' = c ^ ((row>>1)&3)
    const int st_a = srow * BK + (((sq >> 1) ^ ((srow >> 1) & 3)) << 3) + (sq & 1) * 4;

    // ---- A fragment read offset (ushorts); +m*16 rows keeps swizzle invariant ----
    const int arow0 = wrow * 64 + fr;
    const int aoff  = arow0 * BK + ((fc ^ ((arow0 >> 1) & 3)) << 3);

    // ---- B fragment base: per-lane ptr into repacked W ----
    const unsigned short* wfrag = wf + lane * 8;

    f32x4 acc[4][4];
#pragma unroll
    for (int m = 0; m < 4; ++m)
#pragma unroll
        for (int n = 0; n < 4; ++n)
            acc[m][n] = (f32x4){0.f, 0.f, 0.f, 0.f};

    fv4 ra0, ra1;
    auto LOADA = [&](fv4& r, int kb) {
        r = *reinterpret_cast<const fv4*>(xptr + kb * BK);
    };
    auto WRITEA = [&](int buf, const fv4& r) {
        union { unsigned short us[4]; iv2 v; } p;
#pragma unroll
        for (int i = 0; i < 4; ++i) p.us[i] = f2bf(r[i]);
        *reinterpret_cast<iv2*>(&lds_a[buf][st_a]) = p.v;
    };
    auto COMPUTE = [&](int buf, int kb) {
        bf16x8 bfv[4];
#pragma unroll
        for (int n = 0; n < 4; ++n)
            bfv[n] = *reinterpret_cast<const bf16x8*>(
                wfrag + ((wcol * 4 + n) * 16 + kb) * 512);
        bf16x8 af[4];
#pragma unroll
        for (int m = 0; m < 4; ++m)
            af[m] = *reinterpret_cast<const bf16x8*>(&lds_a[buf][aoff + m * 512]);
#pragma unroll
        for (int n = 0; n < 4; ++n)
#pragma unroll
            for (int m = 0; m < 4; ++m)
                acc[m][n] = __builtin_amdgcn_mfma_f32_16x16x32_bf16(
                    af[m], bfv[n], acc[m][n], 0, 0, 0);
    };

    LOADA(ra0, 0);
    LOADA(ra1, 1);
    WRITEA(0, ra0);
    __syncthreads();

    for (int kb = 0; kb < NKSTEP; kb += 2) {
        COMPUTE(0, kb);
        if (kb + 2 < NKSTEP) LOADA(ra0, kb + 2);
        WRITEA(1, ra1);
        __syncthreads();
        COMPUTE(1, kb + 1);
        if (kb + 3 < NKSTEP) LOADA(ra1, kb + 3);
        if (kb + 2 < NKSTEP) WRITEA(0, ra0);
        __syncthreads();
    }

    // ---- epilogue: bias + store ----
    float bv[4];
#pragma unroll
    for (int n = 0; n < 4; ++n)
        bv[n] = bias[wcol * 64 + n * 16 + fr];

    float* obase = out + (rowbase + wrow * 64 + fc * 4) * NDIM + wcol * 64 + fr;
#pragma unroll
    for (int m = 0; m < 4; ++m)
#pragma unroll
        for (int j = 0; j < 4; ++j) {
            float* orow = obase + (m * 16 + j) * NDIM;
#pragma unroll
            for (int n = 0; n < 4; ++n)
                orow[n * 16] = acc[m][n][j] + bv[n];
        }
}

extern "C" void kernel_launch(void* const* d_in, const int* in_sizes, int n_in,
                              void* d_out, int out_size, void* d_ws, size_t ws_size,
                              hipStream_t stream) {
    const float* x    = (const float*)d_in[0];
    const float* w    = (const float*)d_in[1];
    const float* bias = (const float*)d_in[2];
    float* out        = (float*)d_out;
    unsigned short* wf = (unsigned short*)d_ws;  // 512 KB

    hipLaunchKernelGGL(repack_w_kernel, dim3(128), dim3(256), 0, stream, w, wf);
    hipLaunchKernelGGL(linear_bf16_kernel, dim3(M_TOTAL / BM), dim3(1024), 0, stream,
                       x, wf, bias, out);
}